// Round 10
// baseline (834.579 us; speedup 1.0000x reference)
//
#include <hip/hip_runtime.h>
#include <hip/hip_fp16.h>
#include <math.h>

#define N_NODES 131072
#define N_EDGES 2097152
#define DIM     64
#define BSUB    4096
#define NREL    3
#define NBASES  2

typedef unsigned short u16;
typedef unsigned int u32;
typedef __attribute__((ext_vector_type(8))) short bf16x8;   // MFMA A/B frag (4 VGPRs)
typedef __attribute__((ext_vector_type(4))) float f32x4;    // MFMA C/D frag

__device__ __forceinline__ float bf2f(u16 x) {
    return __uint_as_float(((u32)x) << 16);
}
__device__ __forceinline__ u16 f2bf(float f) {
    u32 u = __float_as_uint(f);
    u32 r = (u + 0x7FFFu + ((u >> 16) & 1u)) >> 16;   // RNE
    return (u16)r;
}
__device__ __forceinline__ float4 bf4_to_f4(ushort4 u) {
    return make_float4(bf2f(u.x), bf2f(u.y), bf2f(u.z), bf2f(u.w));
}
__device__ __forceinline__ ushort4 f4_to_bf4(float4 v) {
    ushort4 o; o.x = f2bf(v.x); o.y = f2bf(v.y); o.z = f2bf(v.z); o.w = f2bf(v.w);
    return o;
}

// ---------------- init: zero counts + mark centers ----------------
__global__ void initmark_kernel(int* __restrict__ cnt, int* __restrict__ mark) {
    int i = blockIdx.x * 256 + threadIdx.x;
    if (i < N_NODES) { cnt[i] = 0; mark[i] = (i < BSUB) ? 1 : 0; }
}

__global__ void hist_kernel(const int* __restrict__ dst, int* __restrict__ cnt) {
    int e = blockIdx.x * 256 + threadIdx.x;
    if (e < N_EDGES) atomicAdd(&cnt[dst[e]], 1);
}

// mark sources feeding the BSUB centers (benign races: all write 1)
__global__ void mark_kernel(const int* __restrict__ src, const int* __restrict__ dst,
                            int* __restrict__ mark) {
    int e = blockIdx.x * 256 + threadIdx.x;
    if (e < N_EDGES && dst[e] < BSUB) mark[src[e]] = 1;
}

// block-level exclusive scan of 256 ints; block total -> bsum
__global__ void scan1_kernel(const int* __restrict__ cnt, int* __restrict__ scanned,
                             int* __restrict__ bsum) {
    __shared__ int s[256];
    int tid = threadIdx.x;
    int i = blockIdx.x * 256 + tid;
    int v = cnt[i];
    s[tid] = v;
    __syncthreads();
    int val = v;
    for (int off = 1; off < 256; off <<= 1) {
        int tmp = (tid >= off) ? s[tid - off] : 0;
        __syncthreads();
        val += tmp;
        s[tid] = val;
        __syncthreads();
    }
    scanned[i] = val - v;                 // exclusive
    if (tid == 255) bsum[blockIdx.x] = val;
}

// exclusive scan of 512 block sums, in place
__global__ void scan2_kernel(int* __restrict__ bsum) {
    __shared__ int s[512];
    int tid = threadIdx.x;
    int v = bsum[tid];
    s[tid] = v;
    __syncthreads();
    int val = v;
    for (int off = 1; off < 512; off <<= 1) {
        int tmp = (tid >= off) ? s[tid - off] : 0;
        __syncthreads();
        val += tmp;
        s[tid] = val;
        __syncthreads();
    }
    bsum[tid] = val - v;
}

__global__ void scan3_kernel(int* __restrict__ offs, const int* __restrict__ bsum,
                             int* __restrict__ cursor) {
    int i = blockIdx.x * 256 + threadIdx.x;
    int v = offs[i] + bsum[blockIdx.x];
    offs[i] = v;
    cursor[i] = v;
    if (i == 0) offs[N_NODES] = N_EDGES;
}

// compact marked nodes -> list[], write count to nld
__global__ void listfill_kernel(const int* __restrict__ mark, const int* __restrict__ mpref,
                                const int* __restrict__ mbsum, int* __restrict__ list,
                                int* __restrict__ nld) {
    int i = blockIdx.x * 256 + threadIdx.x;
    int pos = mpref[i] + mbsum[blockIdx.x];
    if (mark[i]) list[pos] = i;
    if (i == N_NODES - 1) *nld = pos + mark[i];
}

// single-pass scatter into CSR order; ONE 8B store per edge:
// {src|et<<20, half2(m1,m2)} -> half the dirty lines of the 16B payload
__global__ void fill_kernel(const int* __restrict__ src, const int* __restrict__ dst,
                            const int* __restrict__ et, const float* __restrict__ m1,
                            const float* __restrict__ m2, int* __restrict__ cursor,
                            uint2* __restrict__ csr) {
    int e = blockIdx.x * 256 + threadIdx.x;
    if (e >= N_EDGES) return;
    int d = dst[e];
    int p = atomicAdd(&cursor[d], 1);
    uint2 v;
    v.x = src[e] | (et[e] << 20);
    u32 lo = __half_as_ushort(__float2half(m1[e]));
    u32 hi = __half_as_ushort(__float2half(m2[e]));
    v.y = lo | (hi << 16);
    csr[p] = v;
}

// ---------------- x -> bf16 convert ----------------
__global__ void cvt_kernel(const float4* __restrict__ x, ushort4* __restrict__ hb, int n4) {
    int i = blockIdx.x * 256 + threadIdx.x;
    if (i < n4) hb[i] = f4_to_bf4(x[i]);
}

// ---------------- weight packing into MFMA B-fragment layout ----------------
// Wc[192][64]: rows 0..63 = V_b0, 64..127 = V_b1, 128..191 = W_self.
// wfrag[conv][nt(4)][kidx(6)][lane(64)][j(8)]; n = nt*16+(lane&15),
// k = kidx*32+(lane>>4)*8+j.
__global__ void wpack_kernel(const float* __restrict__ lV, const float* __restrict__ lW,
                             const float* __restrict__ gV, const float* __restrict__ gW,
                             u16* __restrict__ wfrag) {
    int idx = blockIdx.x * 256 + threadIdx.x;   // 6*4*6*64 = 9216
    if (idx >= 6 * 4 * 6 * 64) return;
    int lane = idx & 63;
    int kidx = (idx >> 6) % 6;
    int nt   = (idx >> 6) / 6 % 4;
    int c    = idx / (64 * 6 * 4);      // conv 0..5
    int layer = c >> 1;
    bool isglobal = c & 1;
    const float* V = isglobal ? gV : lV;
    const float* W = isglobal ? gW : lW;
    int n = nt * 16 + (lane & 15);
    int kbase = kidx * 32 + (lane >> 4) * 8;
    u16 vals[8];
#pragma unroll
    for (int j = 0; j < 8; j++) {
        int r = kbase + j;      // 0..191
        float val;
        if (r < NBASES * DIM) {
            int b = r >> 6, d = r & 63;
            val = V[((layer * NBASES + b) * DIM + d) * DIM + n];
        } else {
            int d = r - NBASES * DIM;
            val = W[(layer * DIM + d) * DIM + n];
        }
        vals[j] = f2bf(val);
    }
    ushort4* o = (ushort4*)(wfrag + (size_t)idx * 8);
    o[0] = make_ushort4(vals[0], vals[1], vals[2], vals[3]);
    o[1] = make_ushort4(vals[4], vals[5], vals[6], vals[7]);
}

// ---------------- fused RelGraphConv: agg + MFMA gemm + epilogue ----------------
// DOUBLE-BUFFERED: reads hin (never written this dispatch), writes hout.
// Block = 256 thr / 4 waves handles 16 dst nodes: wave w aggregates nodes
// 4w..4w+3 (quarter-wave float4 gathers from bf16 hin), stages u_b0|u_b1|h rows
// into a 16x200 LDS tile (stride 200 bf16 -> 2-way bank alias = free), one
// barrier, then wave w computes the 16-row x 16-col MFMA slice (nt = w) over
// K=192 (kidx 0..3 basis from agg, 4..5 self-loop from hin) and applies
// bias+activation, writing hout (bf16) and optionally subg (fp32).
// which: 0 -> m1 (lo half), 1 -> m2 (hi half).
// list != nullptr: rows are list[base+m] for base+m < *nld (pruned conv).
__global__ __launch_bounds__(256) void conv_kernel(
    const ushort4* __restrict__ hin, const int* __restrict__ offs,
    const uint2* __restrict__ csr, const float* __restrict__ Cc,
    int which, const u16* __restrict__ wfrag, const float* __restrict__ bias,
    u16* __restrict__ hout, float* __restrict__ subg, int subg_off, int act,
    int nNodes, const int* __restrict__ list, const int* __restrict__ nld) {
    __shared__ u16 tile[16][200];
    int tid = threadIdx.x;
    int wave = tid >> 6, lane = tid & 63;
    int q  = lane >> 4;     // quarter 0..3
    int ql = lane & 15;     // lane within quarter
    int nL = list ? *nld : nNodes;
    int base = blockIdx.x * 16;
    if (base >= nL) return;
    float Ca0 = Cc[0], Cb0 = Cc[1], Ca1 = Cc[2], Cb1 = Cc[3], Ca2 = Cc[4], Cb2 = Cc[5];

    // ---- phase 1: aggregate 4 nodes per wave ----
    for (int i = 0; i < 4; i++) {
        int m = wave * 4 + i;          // LDS tile row
        int idx = base + m;
        bool valid = idx < nL;
        int n = valid ? (list ? list[idx] : idx) : 0;
        float4 a0 = make_float4(0.f, 0.f, 0.f, 0.f);
        float4 a1 = make_float4(0.f, 0.f, 0.f, 0.f);
        if (valid) {
            int beg = offs[n], end = offs[n + 1];
            for (int bb = beg; bb < end; bb += 64) {
                int cnt = min(64, end - bb);
                int p = 0; float mval = 0.f;
                if (lane < cnt) {
                    uint2 meta = csr[bb + lane];
                    p = meta.x;
                    u16 hm = which ? (u16)(meta.y >> 16) : (u16)(meta.y & 0xFFFF);
                    mval = __half2float(__ushort_as_half(hm));
                }
                for (int j = 0; j < cnt; j += 32) {
                    int pe[8]; float me[8]; ushort4 r[8];
#pragma unroll
                    for (int s = 0; s < 8; s++) {
                        int jj = j + (s << 2) + q;
                        int ii = jj < cnt ? jj : 0;
                        pe[s] = __shfl(p, ii, 64);
                        float mm = __shfl(mval, ii, 64);
                        me[s] = jj < cnt ? mm : 0.f;
                    }
#pragma unroll
                    for (int s = 0; s < 8; s++)
                        r[s] = hin[((pe[s] & 0xFFFFF) << 4) + ql];
#pragma unroll
                    for (int s = 0; s < 8; s++) {
                        float4 v = bf4_to_f4(r[s]);
                        int et = pe[s] >> 20;
                        float ca = et == 0 ? Ca0 : (et == 1 ? Ca1 : Ca2);
                        float cb = et == 0 ? Cb0 : (et == 1 ? Cb1 : Cb2);
                        float c0 = me[s] * ca, c1 = me[s] * cb;
                        a0.x = fmaf(c0, v.x, a0.x); a0.y = fmaf(c0, v.y, a0.y);
                        a0.z = fmaf(c0, v.z, a0.z); a0.w = fmaf(c0, v.w, a0.w);
                        a1.x = fmaf(c1, v.x, a1.x); a1.y = fmaf(c1, v.y, a1.y);
                        a1.z = fmaf(c1, v.z, a1.z); a1.w = fmaf(c1, v.w, a1.w);
                    }
                }
            }
#pragma unroll
            for (int off = 16; off < 64; off <<= 1) {
                a0.x += __shfl_xor(a0.x, off, 64); a0.y += __shfl_xor(a0.y, off, 64);
                a0.z += __shfl_xor(a0.z, off, 64); a0.w += __shfl_xor(a0.w, off, 64);
                a1.x += __shfl_xor(a1.x, off, 64); a1.y += __shfl_xor(a1.y, off, 64);
                a1.z += __shfl_xor(a1.z, off, 64); a1.w += __shfl_xor(a1.w, off, 64);
            }
        }
        // stage LDS row m: [0:64]=u_b0, [64:128]=u_b1, [128:192]=h[n]
        if (q < 2) {
            ushort4 outv = valid ? f4_to_bf4(q == 0 ? a0 : a1)
                                 : make_ushort4(0, 0, 0, 0);
            *(ushort4*)&tile[m][(q << 6) + (ql << 2)] = outv;
        } else if (q == 2) {
            ushort4 hv = valid ? hin[(n << 4) + ql] : make_ushort4(0, 0, 0, 0);
            *(ushort4*)&tile[m][128 + (ql << 2)] = hv;
        }
    }
    __syncthreads();

    // ---- phase 2: wave w = n-tile w; 16 rows x 16 cols, K = 192 ----
    int l16 = lane & 15, quad = lane >> 4;
    const u16* wf = wfrag + (size_t)wave * (6 * 64 * 8);
    f32x4 acc = {0.f, 0.f, 0.f, 0.f};
#pragma unroll
    for (int kidx = 0; kidx < 6; kidx++) {
        bf16x8 a = *(const bf16x8*)&tile[l16][kidx * 32 + quad * 8];
        bf16x8 b = *(const bf16x8*)(wf + ((size_t)kidx * 64 + lane) * 8);
        acc = __builtin_amdgcn_mfma_f32_16x16x32_bf16(a, b, acc, 0, 0, 0);
    }
    int col = wave * 16 + l16;
    float bcol = bias[col];
#pragma unroll
    for (int r = 0; r < 4; r++) {
        int m = quad * 4 + r;
        int idx = base + m;
        if (idx >= nL) continue;
        int n = list ? list[idx] : idx;
        float xv = acc[r] + bcol;
        float v = act ? (xv > 0.f ? xv : 0.01f * xv)
                      : (xv > 0.f ? xv : expm1f(xv));
        hout[(size_t)n * 64 + col] = f2bf(v);
        if (subg && n < BSUB)
            subg[(size_t)n * 192 + subg_off + col] = v;
    }
}

// ---------------- MLP head: [4096,192] -> relu 128 -> sigmoid 1 ----------------
__global__ __launch_bounds__(256) void head_kernel(
    const float* __restrict__ subg, const float* __restrict__ w1,
    const float* __restrict__ b1, const float* __restrict__ w2,
    const float* __restrict__ b2, float* __restrict__ out) {
    __shared__ float srow[4][192];
    int lane = threadIdx.x & 63, wid = threadIdx.x >> 6;
    int row = blockIdx.x * 4 + wid;
    const float* sr = subg + (size_t)row * 192;
    srow[wid][lane] = sr[lane];
    srow[wid][64 + lane] = sr[64 + lane];
    srow[wid][128 + lane] = sr[128 + lane];
    __syncthreads();
    float acc1 = b1[lane], acc2 = b1[64 + lane];
    const float* w1a = w1 + lane * 192;
    const float* w1b = w1 + (64 + lane) * 192;
    for (int k = 0; k < 192; k++) {
        float s = srow[wid][k];
        acc1 = fmaf(s, w1a[k], acc1);
        acc2 = fmaf(s, w1b[k], acc2);
    }
    acc1 = fmaxf(acc1, 0.f);
    acc2 = fmaxf(acc2, 0.f);
    float part = acc1 * w2[lane] + acc2 * w2[64 + lane];
    for (int off = 32; off; off >>= 1) part += __shfl_down(part, off, 64);
    if (lane == 0) out[row] = 1.f / (1.f + expf(-(part + b2[0])));
}

extern "C" void kernel_launch(void* const* d_in, const int* in_sizes, int n_in,
                              void* d_out, int out_size, void* d_ws, size_t ws_size,
                              hipStream_t stream) {
    const float* x     = (const float*)d_in[0];
    const int*   src   = (const int*)d_in[1];
    const int*   dst   = (const int*)d_in[2];
    const int*   etype = (const int*)d_in[3];
    const float* mask  = (const float*)d_in[4];
    const float* mask2 = (const float*)d_in[5];
    const float* lV = (const float*)d_in[6];
    const float* lC = (const float*)d_in[7];
    const float* lW = (const float*)d_in[8];
    const float* lB = (const float*)d_in[9];
    const float* gV = (const float*)d_in[10];
    const float* gC = (const float*)d_in[11];
    const float* gW = (const float*)d_in[12];
    const float* gB = (const float*)d_in[13];
    const float* w1 = (const float*)d_in[14];
    const float* b1 = (const float*)d_in[15];
    const float* w2 = (const float*)d_in[16];
    const float* b2 = (const float*)d_in[17];
    float* out = (float*)d_out;

    // workspace carve-up
    char* ws = (char*)d_ws;
    size_t off = 0;
    auto alloc = [&](size_t bytes) {
        void* p = ws + off;
        off += (bytes + 255) & ~(size_t)255;
        return p;
    };
    ushort4* h0   = (ushort4*)alloc((size_t)N_NODES * 64 * 2);     // bf16 [N,64] ping
    ushort4* h1   = (ushort4*)alloc((size_t)N_NODES * 64 * 2);     // bf16 [N,64] pong
    uint2* csr    = (uint2*)alloc((size_t)N_EDGES * 8);
    int*   offs   = (int*)alloc((size_t)(N_NODES + 1) * 4);
    int*   cursor = (int*)alloc((size_t)N_NODES * 4);
    int*   bsum   = (int*)alloc(512 * 4);
    int*   mark   = (int*)alloc((size_t)N_NODES * 4);
    int*   mpref  = (int*)alloc((size_t)N_NODES * 4);
    int*   mbsum  = (int*)alloc(512 * 4);
    int*   list   = (int*)alloc((size_t)N_NODES * 4);
    int*   nld    = (int*)alloc(256);
    u16*   wfrag  = (u16*)alloc((size_t)6 * 4 * 6 * 64 * 8 * 2);
    float* subg   = (float*)alloc((size_t)BSUB * 192 * 4);

    // ---- graph preprocessing ----
    initmark_kernel<<<N_NODES / 256, 256, 0, stream>>>(cursor, mark);
    hist_kernel<<<N_EDGES / 256, 256, 0, stream>>>(dst, cursor);
    mark_kernel<<<N_EDGES / 256, 256, 0, stream>>>(src, dst, mark);
    scan1_kernel<<<N_NODES / 256, 256, 0, stream>>>(cursor, offs, bsum);
    scan2_kernel<<<1, 512, 0, stream>>>(bsum);
    scan3_kernel<<<N_NODES / 256, 256, 0, stream>>>(offs, bsum, cursor);
    fill_kernel<<<N_EDGES / 256, 256, 0, stream>>>(src, dst, etype, mask, mask2,
                                                   cursor, csr);
    // frontier compaction for layer-2 local conv
    scan1_kernel<<<N_NODES / 256, 256, 0, stream>>>(mark, mpref, mbsum);
    scan2_kernel<<<1, 512, 0, stream>>>(mbsum);
    listfill_kernel<<<N_NODES / 256, 256, 0, stream>>>(mark, mpref, mbsum, list, nld);
    wpack_kernel<<<(6 * 4 * 6 * 64 + 255) / 256, 256, 0, stream>>>(lV, lW, gV, gW, wfrag);
    cvt_kernel<<<(N_NODES * 64 / 4) / 256, 256, 0, stream>>>((const float4*)x, h0,
                                                             N_NODES * 64 / 4);

    const int convfrag = 4 * 6 * 64 * 8;   // u16 elements per conv
    ushort4* hb[2] = {h0, h1};
    int cur = 0;
    for (int layer = 0; layer < 3; layer++) {
        // local conv (mask=lo half, elu); layer 2: frontier-pruned
        const int* ll = (layer == 2) ? list : nullptr;
        conv_kernel<<<N_NODES / 16, 256, 0, stream>>>(
            hb[cur], offs, csr, lC + layer * NREL * NBASES, 0,
            wfrag + (size_t)(layer * 2 + 0) * convfrag, lB + layer * 64,
            (u16*)hb[cur ^ 1], nullptr, 0, 0, N_NODES, ll, nld);
        cur ^= 1;
        // global conv (mask2=hi half, leaky_relu); layer 2: only BSUB rows
        int nG = (layer == 2) ? BSUB : N_NODES;
        conv_kernel<<<nG / 16, 256, 0, stream>>>(
            hb[cur], offs, csr, gC + layer * NREL * NBASES, 1,
            wfrag + (size_t)(layer * 2 + 1) * convfrag, gB + layer * 64,
            (u16*)hb[cur ^ 1], subg, layer * 64, 1, nG, nullptr, nld);
        cur ^= 1;
    }
    head_kernel<<<BSUB / 4, 256, 0, stream>>>(subg, w1, b1, w2, b2, out);
}

// Round 11
// 823.553 us; speedup vs baseline: 1.0134x; 1.0134x over previous
//
#include <hip/hip_runtime.h>
#include <math.h>

#define N_NODES 131072
#define N_EDGES 2097152
#define DIM     64
#define BSUB    4096
#define NREL    3
#define NBASES  2

typedef unsigned short u16;
typedef __attribute__((ext_vector_type(8))) short bf16x8;   // MFMA A/B frag (4 VGPRs)
typedef __attribute__((ext_vector_type(4))) float f32x4;    // MFMA C/D frag
typedef __attribute__((ext_vector_type(4))) int i32x4;      // for nontemporal 16B store

__device__ __forceinline__ float bf2f(u16 x) {
    return __uint_as_float(((unsigned)x) << 16);
}
__device__ __forceinline__ u16 f2bf(float f) {
    unsigned u = __float_as_uint(f);
    unsigned r = (u + 0x7FFFu + ((u >> 16) & 1u)) >> 16;   // RNE
    return (u16)r;
}
__device__ __forceinline__ float4 bf4_to_f4(ushort4 u) {
    return make_float4(bf2f(u.x), bf2f(u.y), bf2f(u.z), bf2f(u.w));
}
__device__ __forceinline__ ushort4 f4_to_bf4(float4 v) {
    ushort4 o; o.x = f2bf(v.x); o.y = f2bf(v.y); o.z = f2bf(v.z); o.w = f2bf(v.w);
    return o;
}

// ---------------- init: zero counts + mark centers ----------------
__global__ void initmark_kernel(int* __restrict__ cnt, int* __restrict__ mark) {
    int i = blockIdx.x * 256 + threadIdx.x;
    if (i < N_NODES) { cnt[i] = 0; mark[i] = (i < BSUB) ? 1 : 0; }
}

// fused histogram + frontier mark: one pass over (src, dst)
__global__ void histmark_kernel(const int* __restrict__ src, const int* __restrict__ dst,
                                int* __restrict__ cnt, int* __restrict__ mark) {
    int e = blockIdx.x * 256 + threadIdx.x;
    if (e >= N_EDGES) return;
    int d = dst[e];
    atomicAdd(&cnt[d], 1);
    if (d < BSUB) mark[src[e]] = 1;   // benign race: all write 1
}

// block-level exclusive scan of 256 ints; block total -> bsum
__global__ void scan1_kernel(const int* __restrict__ cnt, int* __restrict__ scanned,
                             int* __restrict__ bsum) {
    __shared__ int s[256];
    int tid = threadIdx.x;
    int i = blockIdx.x * 256 + tid;
    int v = cnt[i];
    s[tid] = v;
    __syncthreads();
    int val = v;
    for (int off = 1; off < 256; off <<= 1) {
        int tmp = (tid >= off) ? s[tid - off] : 0;
        __syncthreads();
        val += tmp;
        s[tid] = val;
        __syncthreads();
    }
    scanned[i] = val - v;                 // exclusive
    if (tid == 255) bsum[blockIdx.x] = val;
}

// exclusive scan of 512 block sums, in place
__global__ void scan2_kernel(int* __restrict__ bsum) {
    __shared__ int s[512];
    int tid = threadIdx.x;
    int v = bsum[tid];
    s[tid] = v;
    __syncthreads();
    int val = v;
    for (int off = 1; off < 512; off <<= 1) {
        int tmp = (tid >= off) ? s[tid - off] : 0;
        __syncthreads();
        val += tmp;
        s[tid] = val;
        __syncthreads();
    }
    bsum[tid] = val - v;
}

__global__ void scan3_kernel(int* __restrict__ offs, const int* __restrict__ bsum,
                             int* __restrict__ cursor) {
    int i = blockIdx.x * 256 + threadIdx.x;
    int v = offs[i] + bsum[blockIdx.x];
    offs[i] = v;
    cursor[i] = v;
    if (i == 0) offs[N_NODES] = N_EDGES;
}

// compact marked nodes -> list[], write count to nld
__global__ void listfill_kernel(const int* __restrict__ mark, const int* __restrict__ mpref,
                                const int* __restrict__ mbsum, int* __restrict__ list,
                                int* __restrict__ nld) {
    int i = blockIdx.x * 256 + threadIdx.x;
    int pos = mpref[i] + mbsum[blockIdx.x];
    if (mark[i]) list[pos] = i;
    if (i == N_NODES - 1) *nld = pos + mark[i];
}

// single-pass scatter into CSR order; ONE 16B nontemporal store per edge
// (16B payload proven faster than 8B: fewer edges/line -> less XCD ping-pong)
__global__ void fill_kernel(const int* __restrict__ src, const int* __restrict__ dst,
                            const int* __restrict__ et, const float* __restrict__ m1,
                            const float* __restrict__ m2, int* __restrict__ cursor,
                            i32x4* __restrict__ csr) {
    int e = blockIdx.x * 256 + threadIdx.x;
    if (e >= N_EDGES) return;
    int d = dst[e];
    int p = atomicAdd(&cursor[d], 1);
    i32x4 v;
    v.x = src[e] | (et[e] << 20);
    v.y = __float_as_int(m1[e]);
    v.z = __float_as_int(m2[e]);
    v.w = 0;
    __builtin_nontemporal_store(v, &csr[p]);
}

// ---------------- x -> bf16 convert ----------------
__global__ void cvt_kernel(const float4* __restrict__ x, ushort4* __restrict__ hb, int n4) {
    int i = blockIdx.x * 256 + threadIdx.x;
    if (i < n4) hb[i] = f4_to_bf4(x[i]);
}

// ---------------- weight packing into MFMA B-fragment layout ----------------
// Wc[192][64]: rows 0..63 = V_b0, 64..127 = V_b1, 128..191 = W_self.
// wfrag[conv][nt(4)][kidx(6)][lane(64)][j(8)]; n = nt*16+(lane&15),
// k = kidx*32+(lane>>4)*8+j.
__global__ void wpack_kernel(const float* __restrict__ lV, const float* __restrict__ lW,
                             const float* __restrict__ gV, const float* __restrict__ gW,
                             u16* __restrict__ wfrag) {
    int idx = blockIdx.x * 256 + threadIdx.x;   // 6*4*6*64 = 9216
    if (idx >= 6 * 4 * 6 * 64) return;
    int lane = idx & 63;
    int kidx = (idx >> 6) % 6;
    int nt   = (idx >> 6) / 6 % 4;
    int c    = idx / (64 * 6 * 4);      // conv 0..5
    int layer = c >> 1;
    bool isglobal = c & 1;
    const float* V = isglobal ? gV : lV;
    const float* W = isglobal ? gW : lW;
    int n = nt * 16 + (lane & 15);
    int kbase = kidx * 32 + (lane >> 4) * 8;
    u16 vals[8];
#pragma unroll
    for (int j = 0; j < 8; j++) {
        int r = kbase + j;      // 0..191
        float val;
        if (r < NBASES * DIM) {
            int b = r >> 6, d = r & 63;
            val = V[((layer * NBASES + b) * DIM + d) * DIM + n];
        } else {
            int d = r - NBASES * DIM;
            val = W[(layer * DIM + d) * DIM + n];
        }
        vals[j] = f2bf(val);
    }
    ushort4* o = (ushort4*)(wfrag + (size_t)idx * 8);
    o[0] = make_ushort4(vals[0], vals[1], vals[2], vals[3]);
    o[1] = make_ushort4(vals[4], vals[5], vals[6], vals[7]);
}

// ---------------- edge aggregation (wave per dst node, basis-space, bf16 h) ------
// h: bf16 [N,64]. t: bf16 [N,128] (u_b0 | u_b1; self-loop folded into gemm).
// Quarter-wave gathers: lanes q*16..+15 fetch edge j+4s+q's 128B row.
// which: 0 -> m1 (csr.y), 1 -> m2 (csr.z).
// list != nullptr: process list[idx] for idx < *nld (layer-2 local pruning).
__global__ __launch_bounds__(256) void agg_kernel(
    const ushort4* __restrict__ hb, const int* __restrict__ offs,
    const int4* __restrict__ csr, const float* __restrict__ Cc,
    int which, ushort4* __restrict__ t, int nNodes,
    const int* __restrict__ list, const int* __restrict__ nld) {
    int lane = threadIdx.x & 63;
    int idx = (blockIdx.x << 2) + (threadIdx.x >> 6);
    int n;
    if (list) {
        if (idx >= *nld) return;
        n = list[idx];
    } else {
        if (idx >= nNodes) return;
        n = idx;
    }
    int q  = lane >> 4;     // quarter 0..3
    int ql = lane & 15;     // lane within quarter
    float Ca0 = Cc[0], Cb0 = Cc[1], Ca1 = Cc[2], Cb1 = Cc[3], Ca2 = Cc[4], Cb2 = Cc[5];
    int beg = offs[n], end = offs[n + 1];
    float4 a0 = make_float4(0.f, 0.f, 0.f, 0.f);
    float4 a1 = make_float4(0.f, 0.f, 0.f, 0.f);
    for (int base = beg; base < end; base += 64) {
        int cnt = min(64, end - base);
        int p = 0; float m = 0.f;
        if (lane < cnt) {
            int4 meta = csr[base + lane];
            p = meta.x;
            m = __int_as_float(which ? meta.z : meta.y);
        }
        for (int j = 0; j < cnt; j += 32) {
            int pe[8]; float me[8]; ushort4 r[8];
#pragma unroll
            for (int s = 0; s < 8; s++) {
                int jj = j + (s << 2) + q;
                int ii = jj < cnt ? jj : 0;
                pe[s] = __shfl(p, ii, 64);
                float mm = __shfl(m, ii, 64);
                me[s] = jj < cnt ? mm : 0.f;
            }
#pragma unroll
            for (int s = 0; s < 8; s++)
                r[s] = hb[((pe[s] & 0xFFFFF) << 4) + ql];
#pragma unroll
            for (int s = 0; s < 8; s++) {
                float4 v = bf4_to_f4(r[s]);
                int et = pe[s] >> 20;
                float ca = et == 0 ? Ca0 : (et == 1 ? Ca1 : Ca2);
                float cb = et == 0 ? Cb0 : (et == 1 ? Cb1 : Cb2);
                float c0 = me[s] * ca, c1 = me[s] * cb;
                a0.x = fmaf(c0, v.x, a0.x); a0.y = fmaf(c0, v.y, a0.y);
                a0.z = fmaf(c0, v.z, a0.z); a0.w = fmaf(c0, v.w, a0.w);
                a1.x = fmaf(c1, v.x, a1.x); a1.y = fmaf(c1, v.y, a1.y);
                a1.z = fmaf(c1, v.z, a1.z); a1.w = fmaf(c1, v.w, a1.w);
            }
        }
    }
#pragma unroll
    for (int off = 16; off < 64; off <<= 1) {
        a0.x += __shfl_xor(a0.x, off, 64); a0.y += __shfl_xor(a0.y, off, 64);
        a0.z += __shfl_xor(a0.z, off, 64); a0.w += __shfl_xor(a0.w, off, 64);
        a1.x += __shfl_xor(a1.x, off, 64); a1.y += __shfl_xor(a1.y, off, 64);
        a1.z += __shfl_xor(a1.z, off, 64); a1.w += __shfl_xor(a1.w, off, 64);
    }
    ushort4 outv = f4_to_bf4(q == 0 ? a0 : a1);
    if (q < 2)
        t[(size_t)n * 32 + (q << 4) + ql] = outv;
}

// ---------------- MFMA GEMM: [rows,128(t)|64(h self)] @ wfrag[192,64] -----------
// 4 waves/block; wave owns 16 row-slots x 64 cols; K = 6 x mfma_f32_16x16x32_bf16
// (kidx 0..3 A from t, kidx 4..5 A from h). list: indirect rows (layer-2 local).
__global__ __launch_bounds__(256) void gemm_kernel(
    const u16* __restrict__ t, const u16* __restrict__ h,
    const u16* __restrict__ wfrag, const float* __restrict__ bias,
    u16* __restrict__ hout, float* __restrict__ subg, int subg_off, int act,
    const int* __restrict__ list, const int* __restrict__ nld) {
    int tid = threadIdx.x;
    int wave = tid >> 6, lane = tid & 63;
    int l16 = lane & 15, quad = lane >> 4;
    int nL = list ? *nld : 0;
    if (list && blockIdx.x * 64 >= nL) return;
    int slot0 = blockIdx.x * 64 + wave * 16;
    int myslot = slot0 + l16;
    int rowA = list ? list[min(myslot, nL - 1)] : myslot;
    const u16* trow = t + (size_t)rowA * 128;
    const u16* hrow = h + (size_t)rowA * 64;
    f32x4 acc0 = {0.f, 0.f, 0.f, 0.f};
    f32x4 acc1 = {0.f, 0.f, 0.f, 0.f};
    f32x4 acc2 = {0.f, 0.f, 0.f, 0.f};
    f32x4 acc3 = {0.f, 0.f, 0.f, 0.f};
#pragma unroll
    for (int kidx = 0; kidx < 6; kidx++) {
        bf16x8 a = (kidx < 4)
            ? *(const bf16x8*)(trow + kidx * 32 + quad * 8)
            : *(const bf16x8*)(hrow + (kidx - 4) * 32 + quad * 8);
        bf16x8 b0 = *(const bf16x8*)(wfrag + ((size_t)(0 * 6 + kidx) * 64 + lane) * 8);
        bf16x8 b1 = *(const bf16x8*)(wfrag + ((size_t)(1 * 6 + kidx) * 64 + lane) * 8);
        bf16x8 b2 = *(const bf16x8*)(wfrag + ((size_t)(2 * 6 + kidx) * 64 + lane) * 8);
        bf16x8 b3 = *(const bf16x8*)(wfrag + ((size_t)(3 * 6 + kidx) * 64 + lane) * 8);
        acc0 = __builtin_amdgcn_mfma_f32_16x16x32_bf16(a, b0, acc0, 0, 0, 0);
        acc1 = __builtin_amdgcn_mfma_f32_16x16x32_bf16(a, b1, acc1, 0, 0, 0);
        acc2 = __builtin_amdgcn_mfma_f32_16x16x32_bf16(a, b2, acc2, 0, 0, 0);
        acc3 = __builtin_amdgcn_mfma_f32_16x16x32_bf16(a, b3, acc3, 0, 0, 0);
    }
    float accs[4][4] = {
        {acc0[0], acc0[1], acc0[2], acc0[3]},
        {acc1[0], acc1[1], acc1[2], acc1[3]},
        {acc2[0], acc2[1], acc2[2], acc2[3]},
        {acc3[0], acc3[1], acc3[2], acc3[3]},
    };
#pragma unroll
    for (int nt = 0; nt < 4; nt++) {
        int col = nt * 16 + l16;
        float bcol = bias[col];
#pragma unroll
        for (int r = 0; r < 4; r++) {
            int cslot = slot0 + quad * 4 + r;
            if (list && cslot >= nL) continue;
            int row = list ? __shfl(rowA, quad * 4 + r, 64) : cslot;
            float xv = accs[nt][r] + bcol;
            float v = act ? (xv > 0.f ? xv : 0.01f * xv)
                          : (xv > 0.f ? xv : expm1f(xv));
            hout[(size_t)row * 64 + col] = f2bf(v);
            if (subg && row < BSUB)
                subg[(size_t)row * 192 + subg_off + col] = v;
        }
    }
}

// ---------------- MLP head: [4096,192] -> relu 128 -> sigmoid 1 ----------------
__global__ __launch_bounds__(256) void head_kernel(
    const float* __restrict__ subg, const float* __restrict__ w1,
    const float* __restrict__ b1, const float* __restrict__ w2,
    const float* __restrict__ b2, float* __restrict__ out) {
    __shared__ float srow[4][192];
    int lane = threadIdx.x & 63, wid = threadIdx.x >> 6;
    int row = blockIdx.x * 4 + wid;
    const float* sr = subg + (size_t)row * 192;
    srow[wid][lane] = sr[lane];
    srow[wid][64 + lane] = sr[64 + lane];
    srow[wid][128 + lane] = sr[128 + lane];
    __syncthreads();
    float acc1 = b1[lane], acc2 = b1[64 + lane];
    const float* w1a = w1 + lane * 192;
    const float* w1b = w1 + (64 + lane) * 192;
    for (int k = 0; k < 192; k++) {
        float s = srow[wid][k];
        acc1 = fmaf(s, w1a[k], acc1);
        acc2 = fmaf(s, w1b[k], acc2);
    }
    acc1 = fmaxf(acc1, 0.f);
    acc2 = fmaxf(acc2, 0.f);
    float part = acc1 * w2[lane] + acc2 * w2[64 + lane];
    for (int off = 32; off; off >>= 1) part += __shfl_down(part, off, 64);
    if (lane == 0) out[row] = 1.f / (1.f + expf(-(part + b2[0])));
}

extern "C" void kernel_launch(void* const* d_in, const int* in_sizes, int n_in,
                              void* d_out, int out_size, void* d_ws, size_t ws_size,
                              hipStream_t stream) {
    const float* x     = (const float*)d_in[0];
    const int*   src   = (const int*)d_in[1];
    const int*   dst   = (const int*)d_in[2];
    const int*   etype = (const int*)d_in[3];
    const float* mask  = (const float*)d_in[4];
    const float* mask2 = (const float*)d_in[5];
    const float* lV = (const float*)d_in[6];
    const float* lC = (const float*)d_in[7];
    const float* lW = (const float*)d_in[8];
    const float* lB = (const float*)d_in[9];
    const float* gV = (const float*)d_in[10];
    const float* gC = (const float*)d_in[11];
    const float* gW = (const float*)d_in[12];
    const float* gB = (const float*)d_in[13];
    const float* w1 = (const float*)d_in[14];
    const float* b1 = (const float*)d_in[15];
    const float* w2 = (const float*)d_in[16];
    const float* b2 = (const float*)d_in[17];
    float* out = (float*)d_out;

    // workspace carve-up
    char* ws = (char*)d_ws;
    size_t off = 0;
    auto alloc = [&](size_t bytes) {
        void* p = ws + off;
        off += (bytes + 255) & ~(size_t)255;
        return p;
    };
    ushort4* h    = (ushort4*)alloc((size_t)N_NODES * 64 * 2);     // bf16 [N,64]
    ushort4* t    = (ushort4*)alloc((size_t)N_NODES * 128 * 2);    // bf16 [N,128]
    i32x4* csr    = (i32x4*)alloc((size_t)N_EDGES * 16);
    int*   offs   = (int*)alloc((size_t)(N_NODES + 1) * 4);
    int*   cursor = (int*)alloc((size_t)N_NODES * 4);
    int*   bsum   = (int*)alloc(512 * 4);
    int*   mark   = (int*)alloc((size_t)N_NODES * 4);
    int*   mpref  = (int*)alloc((size_t)N_NODES * 4);
    int*   mbsum  = (int*)alloc(512 * 4);
    int*   list   = (int*)alloc((size_t)N_NODES * 4);
    int*   nld    = (int*)alloc(256);
    u16*   wfrag  = (u16*)alloc((size_t)6 * 4 * 6 * 64 * 8 * 2);
    float* subg   = (float*)alloc((size_t)BSUB * 192 * 4);

    // ---- graph preprocessing ----
    initmark_kernel<<<N_NODES / 256, 256, 0, stream>>>(cursor, mark);
    histmark_kernel<<<N_EDGES / 256, 256, 0, stream>>>(src, dst, cursor, mark);
    scan1_kernel<<<N_NODES / 256, 256, 0, stream>>>(cursor, offs, bsum);
    scan2_kernel<<<1, 512, 0, stream>>>(bsum);
    scan3_kernel<<<N_NODES / 256, 256, 0, stream>>>(offs, bsum, cursor);
    fill_kernel<<<N_EDGES / 256, 256, 0, stream>>>(src, dst, etype, mask, mask2,
                                                   cursor, csr);
    // frontier compaction for layer-2 local conv
    scan1_kernel<<<N_NODES / 256, 256, 0, stream>>>(mark, mpref, mbsum);
    scan2_kernel<<<1, 512, 0, stream>>>(mbsum);
    listfill_kernel<<<N_NODES / 256, 256, 0, stream>>>(mark, mpref, mbsum, list, nld);
    wpack_kernel<<<(6 * 4 * 6 * 64 + 255) / 256, 256, 0, stream>>>(lV, lW, gV, gW, wfrag);
    cvt_kernel<<<(N_NODES * 64 / 4) / 256, 256, 0, stream>>>((const float4*)x, h,
                                                             N_NODES * 64 / 4);

    const int convfrag = 4 * 6 * 64 * 8;   // u16 elements per conv
    for (int layer = 0; layer < 3; layer++) {
        // local conv (mask, elu); layer 2: frontier-pruned
        const int* ll  = (layer == 2) ? list : nullptr;
        agg_kernel<<<N_NODES / 4, 256, 0, stream>>>(h, offs, (const int4*)csr,
            lC + layer * NREL * NBASES, 0, t, N_NODES, ll, nld);
        gemm_kernel<<<N_NODES / 64, 256, 0, stream>>>(
            (const u16*)t, (const u16*)h,
            wfrag + (size_t)(layer * 2 + 0) * convfrag, lB + layer * 64,
            (u16*)h, nullptr, 0, 0, ll, nld);
        // global conv (mask2, leaky_relu); layer 2: only BSUB rows
        int nG = (layer == 2) ? BSUB : N_NODES;
        agg_kernel<<<(nG + 3) / 4, 256, 0, stream>>>(h, offs, (const int4*)csr,
            gC + layer * NREL * NBASES, 1, t, nG, nullptr, nld);
        gemm_kernel<<<nG / 64, 256, 0, stream>>>(
            (const u16*)t, (const u16*)h,
            wfrag + (size_t)(layer * 2 + 1) * convfrag, gB + layer * 64,
            (u16*)h, subg, layer * 64, 1, nullptr, nld);
    }
    head_kernel<<<BSUB / 4, 256, 0, stream>>>(subg, w1, b1, w2, b2, out);
}

// Round 12
// 788.398 us; speedup vs baseline: 1.0586x; 1.0446x over previous
//
#include <hip/hip_runtime.h>
#include <math.h>

#define N_NODES 131072
#define N_EDGES 2097152
#define DIM     64
#define BSUB    4096
#define NREL    3
#define NBASES  2

typedef unsigned short u16;
typedef __attribute__((ext_vector_type(8))) short bf16x8;   // MFMA A/B frag (4 VGPRs)
typedef __attribute__((ext_vector_type(4))) float f32x4;    // MFMA C/D frag

__device__ __forceinline__ float bf2f(u16 x) {
    return __uint_as_float(((unsigned)x) << 16);
}
__device__ __forceinline__ u16 f2bf(float f) {
    unsigned u = __float_as_uint(f);
    unsigned r = (u + 0x7FFFu + ((u >> 16) & 1u)) >> 16;   // RNE
    return (u16)r;
}
__device__ __forceinline__ float4 bf4_to_f4(ushort4 u) {
    return make_float4(bf2f(u.x), bf2f(u.y), bf2f(u.z), bf2f(u.w));
}
__device__ __forceinline__ ushort4 f4_to_bf4(float4 v) {
    ushort4 o; o.x = f2bf(v.x); o.y = f2bf(v.y); o.z = f2bf(v.z); o.w = f2bf(v.w);
    return o;
}

// ---------------- init: zero counts + mark centers ----------------
__global__ void initmark_kernel(int* __restrict__ cnt, int* __restrict__ mark) {
    int i = blockIdx.x * 256 + threadIdx.x;
    if (i < N_NODES) { cnt[i] = 0; mark[i] = (i < BSUB) ? 1 : 0; }
}

// fused histogram + frontier mark: one pass over (src, dst)
__global__ void histmark_kernel(const int* __restrict__ src, const int* __restrict__ dst,
                                int* __restrict__ cnt, int* __restrict__ mark) {
    int e = blockIdx.x * 256 + threadIdx.x;
    if (e >= N_EDGES) return;
    int d = dst[e];
    atomicAdd(&cnt[d], 1);
    if (d < BSUB) mark[src[e]] = 1;   // benign race: all write 1
}

// block-level exclusive scan of 256 ints; block total -> bsum
__global__ void scan1_kernel(const int* __restrict__ cnt, int* __restrict__ scanned,
                             int* __restrict__ bsum) {
    __shared__ int s[256];
    int tid = threadIdx.x;
    int i = blockIdx.x * 256 + tid;
    int v = cnt[i];
    s[tid] = v;
    __syncthreads();
    int val = v;
    for (int off = 1; off < 256; off <<= 1) {
        int tmp = (tid >= off) ? s[tid - off] : 0;
        __syncthreads();
        val += tmp;
        s[tid] = val;
        __syncthreads();
    }
    scanned[i] = val - v;                 // exclusive
    if (tid == 255) bsum[blockIdx.x] = val;
}

// exclusive scan of 512 block sums, in place
__global__ void scan2_kernel(int* __restrict__ bsum) {
    __shared__ int s[512];
    int tid = threadIdx.x;
    int v = bsum[tid];
    s[tid] = v;
    __syncthreads();
    int val = v;
    for (int off = 1; off < 512; off <<= 1) {
        int tmp = (tid >= off) ? s[tid - off] : 0;
        __syncthreads();
        val += tmp;
        s[tid] = val;
        __syncthreads();
    }
    bsum[tid] = val - v;
}

__global__ void scan3_kernel(int* __restrict__ offs, const int* __restrict__ bsum,
                             int* __restrict__ cursor) {
    int i = blockIdx.x * 256 + threadIdx.x;
    int v = offs[i] + bsum[blockIdx.x];
    offs[i] = v;
    cursor[i] = v;
    if (i == 0) offs[N_NODES] = N_EDGES;
}

// compact marked nodes -> list[], write count to nld
__global__ void listfill_kernel(const int* __restrict__ mark, const int* __restrict__ mpref,
                                const int* __restrict__ mbsum, int* __restrict__ list,
                                int* __restrict__ nld) {
    int i = blockIdx.x * 256 + threadIdx.x;
    int pos = mpref[i] + mbsum[blockIdx.x];
    if (mark[i]) list[pos] = i;
    if (i == N_NODES - 1) *nld = pos + mark[i];
}

// single-pass scatter into CSR order; ONE plain 16B store per edge.
// (R8-proven config: 16B payload, normal store. NT store (R11) and 8B payload
// (R10) and two-pass binning (R7) all measured WORSE — L2 is the merge buffer.)
__global__ void fill_kernel(const int* __restrict__ src, const int* __restrict__ dst,
                            const int* __restrict__ et, const float* __restrict__ m1,
                            const float* __restrict__ m2, int* __restrict__ cursor,
                            int4* __restrict__ csr) {
    int e = blockIdx.x * 256 + threadIdx.x;
    if (e >= N_EDGES) return;
    int d = dst[e];
    int p = atomicAdd(&cursor[d], 1);
    int4 v;
    v.x = src[e] | (et[e] << 20);
    v.y = __float_as_int(m1[e]);
    v.z = __float_as_int(m2[e]);
    v.w = 0;
    csr[p] = v;
}

// ---------------- x -> bf16 convert ----------------
__global__ void cvt_kernel(const float4* __restrict__ x, ushort4* __restrict__ hb, int n4) {
    int i = blockIdx.x * 256 + threadIdx.x;
    if (i < n4) hb[i] = f4_to_bf4(x[i]);
}

// ---------------- weight packing into MFMA B-fragment layout ----------------
// Wc[192][64]: rows 0..63 = V_b0, 64..127 = V_b1, 128..191 = W_self.
// wfrag[conv][nt(4)][kidx(6)][lane(64)][j(8)]; n = nt*16+(lane&15),
// k = kidx*32+(lane>>4)*8+j.
__global__ void wpack_kernel(const float* __restrict__ lV, const float* __restrict__ lW,
                             const float* __restrict__ gV, const float* __restrict__ gW,
                             u16* __restrict__ wfrag) {
    int idx = blockIdx.x * 256 + threadIdx.x;   // 6*4*6*64 = 9216
    if (idx >= 6 * 4 * 6 * 64) return;
    int lane = idx & 63;
    int kidx = (idx >> 6) % 6;
    int nt   = (idx >> 6) / 6 % 4;
    int c    = idx / (64 * 6 * 4);      // conv 0..5
    int layer = c >> 1;
    bool isglobal = c & 1;
    const float* V = isglobal ? gV : lV;
    const float* W = isglobal ? gW : lW;
    int n = nt * 16 + (lane & 15);
    int kbase = kidx * 32 + (lane >> 4) * 8;
    u16 vals[8];
#pragma unroll
    for (int j = 0; j < 8; j++) {
        int r = kbase + j;      // 0..191
        float val;
        if (r < NBASES * DIM) {
            int b = r >> 6, d = r & 63;
            val = V[((layer * NBASES + b) * DIM + d) * DIM + n];
        } else {
            int d = r - NBASES * DIM;
            val = W[(layer * DIM + d) * DIM + n];
        }
        vals[j] = f2bf(val);
    }
    ushort4* o = (ushort4*)(wfrag + (size_t)idx * 8);
    o[0] = make_ushort4(vals[0], vals[1], vals[2], vals[3]);
    o[1] = make_ushort4(vals[4], vals[5], vals[6], vals[7]);
}

// ---------------- edge aggregation (wave per dst node, basis-space, bf16 h) ------
// h: bf16 [N,64]. t: bf16 [N,128] (u_b0 | u_b1; self-loop folded into gemm).
// Quarter-wave gathers: lanes q*16..+15 fetch edge j+4s+q's 128B row.
// which: 0 -> m1 (csr.y), 1 -> m2 (csr.z).
// list != nullptr: process list[idx] for idx < *nld (layer-2 local pruning).
__global__ __launch_bounds__(256) void agg_kernel(
    const ushort4* __restrict__ hb, const int* __restrict__ offs,
    const int4* __restrict__ csr, const float* __restrict__ Cc,
    int which, ushort4* __restrict__ t, int nNodes,
    const int* __restrict__ list, const int* __restrict__ nld) {
    int lane = threadIdx.x & 63;
    int idx = (blockIdx.x << 2) + (threadIdx.x >> 6);
    int n;
    if (list) {
        if (idx >= *nld) return;
        n = list[idx];
    } else {
        if (idx >= nNodes) return;
        n = idx;
    }
    int q  = lane >> 4;     // quarter 0..3
    int ql = lane & 15;     // lane within quarter
    float Ca0 = Cc[0], Cb0 = Cc[1], Ca1 = Cc[2], Cb1 = Cc[3], Ca2 = Cc[4], Cb2 = Cc[5];
    int beg = offs[n], end = offs[n + 1];
    float4 a0 = make_float4(0.f, 0.f, 0.f, 0.f);
    float4 a1 = make_float4(0.f, 0.f, 0.f, 0.f);
    for (int base = beg; base < end; base += 64) {
        int cnt = min(64, end - base);
        int p = 0; float m = 0.f;
        if (lane < cnt) {
            int4 meta = csr[base + lane];
            p = meta.x;
            m = __int_as_float(which ? meta.z : meta.y);
        }
        for (int j = 0; j < cnt; j += 32) {
            int pe[8]; float me[8]; ushort4 r[8];
#pragma unroll
            for (int s = 0; s < 8; s++) {
                int jj = j + (s << 2) + q;
                int ii = jj < cnt ? jj : 0;
                pe[s] = __shfl(p, ii, 64);
                float mm = __shfl(m, ii, 64);
                me[s] = jj < cnt ? mm : 0.f;
            }
#pragma unroll
            for (int s = 0; s < 8; s++)
                r[s] = hb[((pe[s] & 0xFFFFF) << 4) + ql];
#pragma unroll
            for (int s = 0; s < 8; s++) {
                float4 v = bf4_to_f4(r[s]);
                int et = pe[s] >> 20;
                float ca = et == 0 ? Ca0 : (et == 1 ? Ca1 : Ca2);
                float cb = et == 0 ? Cb0 : (et == 1 ? Cb1 : Cb2);
                float c0 = me[s] * ca, c1 = me[s] * cb;
                a0.x = fmaf(c0, v.x, a0.x); a0.y = fmaf(c0, v.y, a0.y);
                a0.z = fmaf(c0, v.z, a0.z); a0.w = fmaf(c0, v.w, a0.w);
                a1.x = fmaf(c1, v.x, a1.x); a1.y = fmaf(c1, v.y, a1.y);
                a1.z = fmaf(c1, v.z, a1.z); a1.w = fmaf(c1, v.w, a1.w);
            }
        }
    }
#pragma unroll
    for (int off = 16; off < 64; off <<= 1) {
        a0.x += __shfl_xor(a0.x, off, 64); a0.y += __shfl_xor(a0.y, off, 64);
        a0.z += __shfl_xor(a0.z, off, 64); a0.w += __shfl_xor(a0.w, off, 64);
        a1.x += __shfl_xor(a1.x, off, 64); a1.y += __shfl_xor(a1.y, off, 64);
        a1.z += __shfl_xor(a1.z, off, 64); a1.w += __shfl_xor(a1.w, off, 64);
    }
    ushort4 outv = f4_to_bf4(q == 0 ? a0 : a1);
    if (q < 2)
        t[(size_t)n * 32 + (q << 4) + ql] = outv;
}

// ---------------- MFMA GEMM: [rows,128(t)|64(h self)] @ wfrag[192,64] -----------
// 4 waves/block; wave owns 16 row-slots x 64 cols; K = 6 x mfma_f32_16x16x32_bf16
// (kidx 0..3 A from t, kidx 4..5 A from h). list: indirect rows (layer-2 local).
__global__ __launch_bounds__(256) void gemm_kernel(
    const u16* __restrict__ t, const u16* __restrict__ h,
    const u16* __restrict__ wfrag, const float* __restrict__ bias,
    u16* __restrict__ hout, float* __restrict__ subg, int subg_off, int act,
    const int* __restrict__ list, const int* __restrict__ nld) {
    int tid = threadIdx.x;
    int wave = tid >> 6, lane = tid & 63;
    int l16 = lane & 15, quad = lane >> 4;
    int nL = list ? *nld : 0;
    if (list && blockIdx.x * 64 >= nL) return;
    int slot0 = blockIdx.x * 64 + wave * 16;
    int myslot = slot0 + l16;
    int rowA = list ? list[min(myslot, nL - 1)] : myslot;
    const u16* trow = t + (size_t)rowA * 128;
    const u16* hrow = h + (size_t)rowA * 64;
    f32x4 acc0 = {0.f, 0.f, 0.f, 0.f};
    f32x4 acc1 = {0.f, 0.f, 0.f, 0.f};
    f32x4 acc2 = {0.f, 0.f, 0.f, 0.f};
    f32x4 acc3 = {0.f, 0.f, 0.f, 0.f};
#pragma unroll
    for (int kidx = 0; kidx < 6; kidx++) {
        bf16x8 a = (kidx < 4)
            ? *(const bf16x8*)(trow + kidx * 32 + quad * 8)
            : *(const bf16x8*)(hrow + (kidx - 4) * 32 + quad * 8);
        bf16x8 b0 = *(const bf16x8*)(wfrag + ((size_t)(0 * 6 + kidx) * 64 + lane) * 8);
        bf16x8 b1 = *(const bf16x8*)(wfrag + ((size_t)(1 * 6 + kidx) * 64 + lane) * 8);
        bf16x8 b2 = *(const bf16x8*)(wfrag + ((size_t)(2 * 6 + kidx) * 64 + lane) * 8);
        bf16x8 b3 = *(const bf16x8*)(wfrag + ((size_t)(3 * 6 + kidx) * 64 + lane) * 8);
        acc0 = __builtin_amdgcn_mfma_f32_16x16x32_bf16(a, b0, acc0, 0, 0, 0);
        acc1 = __builtin_amdgcn_mfma_f32_16x16x32_bf16(a, b1, acc1, 0, 0, 0);
        acc2 = __builtin_amdgcn_mfma_f32_16x16x32_bf16(a, b2, acc2, 0, 0, 0);
        acc3 = __builtin_amdgcn_mfma_f32_16x16x32_bf16(a, b3, acc3, 0, 0, 0);
    }
    float accs[4][4] = {
        {acc0[0], acc0[1], acc0[2], acc0[3]},
        {acc1[0], acc1[1], acc1[2], acc1[3]},
        {acc2[0], acc2[1], acc2[2], acc2[3]},
        {acc3[0], acc3[1], acc3[2], acc3[3]},
    };
#pragma unroll
    for (int nt = 0; nt < 4; nt++) {
        int col = nt * 16 + l16;
        float bcol = bias[col];
#pragma unroll
        for (int r = 0; r < 4; r++) {
            int cslot = slot0 + quad * 4 + r;
            if (list && cslot >= nL) continue;
            int row = list ? __shfl(rowA, quad * 4 + r, 64) : cslot;
            float xv = accs[nt][r] + bcol;
            float v = act ? (xv > 0.f ? xv : 0.01f * xv)
                          : (xv > 0.f ? xv : expm1f(xv));
            hout[(size_t)row * 64 + col] = f2bf(v);
            if (subg && row < BSUB)
                subg[(size_t)row * 192 + subg_off + col] = v;
        }
    }
}

// ---------------- MLP head: [4096,192] -> relu 128 -> sigmoid 1 ----------------
__global__ __launch_bounds__(256) void head_kernel(
    const float* __restrict__ subg, const float* __restrict__ w1,
    const float* __restrict__ b1, const float* __restrict__ w2,
    const float* __restrict__ b2, float* __restrict__ out) {
    __shared__ float srow[4][192];
    int lane = threadIdx.x & 63, wid = threadIdx.x >> 6;
    int row = blockIdx.x * 4 + wid;
    const float* sr = subg + (size_t)row * 192;
    srow[wid][lane] = sr[lane];
    srow[wid][64 + lane] = sr[64 + lane];
    srow[wid][128 + lane] = sr[128 + lane];
    __syncthreads();
    float acc1 = b1[lane], acc2 = b1[64 + lane];
    const float* w1a = w1 + lane * 192;
    const float* w1b = w1 + (64 + lane) * 192;
    for (int k = 0; k < 192; k++) {
        float s = srow[wid][k];
        acc1 = fmaf(s, w1a[k], acc1);
        acc2 = fmaf(s, w1b[k], acc2);
    }
    acc1 = fmaxf(acc1, 0.f);
    acc2 = fmaxf(acc2, 0.f);
    float part = acc1 * w2[lane] + acc2 * w2[64 + lane];
    for (int off = 32; off; off >>= 1) part += __shfl_down(part, off, 64);
    if (lane == 0) out[row] = 1.f / (1.f + expf(-(part + b2[0])));
}

extern "C" void kernel_launch(void* const* d_in, const int* in_sizes, int n_in,
                              void* d_out, int out_size, void* d_ws, size_t ws_size,
                              hipStream_t stream) {
    const float* x     = (const float*)d_in[0];
    const int*   src   = (const int*)d_in[1];
    const int*   dst   = (const int*)d_in[2];
    const int*   etype = (const int*)d_in[3];
    const float* mask  = (const float*)d_in[4];
    const float* mask2 = (const float*)d_in[5];
    const float* lV = (const float*)d_in[6];
    const float* lC = (const float*)d_in[7];
    const float* lW = (const float*)d_in[8];
    const float* lB = (const float*)d_in[9];
    const float* gV = (const float*)d_in[10];
    const float* gC = (const float*)d_in[11];
    const float* gW = (const float*)d_in[12];
    const float* gB = (const float*)d_in[13];
    const float* w1 = (const float*)d_in[14];
    const float* b1 = (const float*)d_in[15];
    const float* w2 = (const float*)d_in[16];
    const float* b2 = (const float*)d_in[17];
    float* out = (float*)d_out;

    // workspace carve-up
    char* ws = (char*)d_ws;
    size_t off = 0;
    auto alloc = [&](size_t bytes) {
        void* p = ws + off;
        off += (bytes + 255) & ~(size_t)255;
        return p;
    };
    ushort4* h    = (ushort4*)alloc((size_t)N_NODES * 64 * 2);     // bf16 [N,64]
    ushort4* t    = (ushort4*)alloc((size_t)N_NODES * 128 * 2);    // bf16 [N,128]
    int4*  csr    = (int4*)alloc((size_t)N_EDGES * 16);
    int*   offs   = (int*)alloc((size_t)(N_NODES + 1) * 4);
    int*   cursor = (int*)alloc((size_t)N_NODES * 4);
    int*   bsum   = (int*)alloc(512 * 4);
    int*   mark   = (int*)alloc((size_t)N_NODES * 4);
    int*   mpref  = (int*)alloc((size_t)N_NODES * 4);
    int*   mbsum  = (int*)alloc(512 * 4);
    int*   list   = (int*)alloc((size_t)N_NODES * 4);
    int*   nld    = (int*)alloc(256);
    u16*   wfrag  = (u16*)alloc((size_t)6 * 4 * 6 * 64 * 8 * 2);
    float* subg   = (float*)alloc((size_t)BSUB * 192 * 4);

    // ---- graph preprocessing ----
    initmark_kernel<<<N_NODES / 256, 256, 0, stream>>>(cursor, mark);
    histmark_kernel<<<N_EDGES / 256, 256, 0, stream>>>(src, dst, cursor, mark);
    scan1_kernel<<<N_NODES / 256, 256, 0, stream>>>(cursor, offs, bsum);
    scan2_kernel<<<1, 512, 0, stream>>>(bsum);
    scan3_kernel<<<N_NODES / 256, 256, 0, stream>>>(offs, bsum, cursor);
    fill_kernel<<<N_EDGES / 256, 256, 0, stream>>>(src, dst, etype, mask, mask2,
                                                   cursor, csr);
    // frontier compaction for layer-2 local conv
    scan1_kernel<<<N_NODES / 256, 256, 0, stream>>>(mark, mpref, mbsum);
    scan2_kernel<<<1, 512, 0, stream>>>(mbsum);
    listfill_kernel<<<N_NODES / 256, 256, 0, stream>>>(mark, mpref, mbsum, list, nld);
    wpack_kernel<<<(6 * 4 * 6 * 64 + 255) / 256, 256, 0, stream>>>(lV, lW, gV, gW, wfrag);
    cvt_kernel<<<(N_NODES * 64 / 4) / 256, 256, 0, stream>>>((const float4*)x, h,
                                                             N_NODES * 64 / 4);

    const int convfrag = 4 * 6 * 64 * 8;   // u16 elements per conv
    for (int layer = 0; layer < 3; layer++) {
        // local conv (mask, elu); layer 2: frontier-pruned
        const int* ll  = (layer == 2) ? list : nullptr;
        agg_kernel<<<N_NODES / 4, 256, 0, stream>>>(h, offs, csr,
            lC + layer * NREL * NBASES, 0, t, N_NODES, ll, nld);
        gemm_kernel<<<N_NODES / 64, 256, 0, stream>>>(
            (const u16*)t, (const u16*)h,
            wfrag + (size_t)(layer * 2 + 0) * convfrag, lB + layer * 64,
            (u16*)h, nullptr, 0, 0, ll, nld);
        // global conv (mask2, leaky_relu); layer 2: only BSUB rows
        int nG = (layer == 2) ? BSUB : N_NODES;
        agg_kernel<<<(nG + 3) / 4, 256, 0, stream>>>(h, offs, csr,
            gC + layer * NREL * NBASES, 1, t, nG, nullptr, nld);
        gemm_kernel<<<nG / 64, 256, 0, stream>>>(
            (const u16*)t, (const u16*)h,
            wfrag + (size_t)(layer * 2 + 1) * convfrag, gB + layer * 64,
            (u16*)h, subg, layer * 64, 1, nullptr, nld);
    }
    head_kernel<<<BSUB / 4, 256, 0, stream>>>(subg, w1, b1, w2, b2, out);
}